// Round 4
// baseline (300.785 us; speedup 1.0000x reference)
//
#include <hip/hip_runtime.h>

#define NN 50000
#define NE 500000
#define HID 128
#define MT 782   // ceil(NN/64)

typedef __attribute__((ext_vector_type(8))) short short8;   // 8 bf16 = 16B
typedef __attribute__((ext_vector_type(4))) float f32x4;
typedef unsigned short ushort_t;
typedef unsigned int uint32;

__device__ __forceinline__ float bflo(uint32 u) {
    union { float f; uint32 i; } x; x.i = u << 16; return x.f;
}
__device__ __forceinline__ float bfhi(uint32 u) {
    union { float f; uint32 i; } x; x.i = u & 0xffff0000u; return x.f;
}
__device__ __forceinline__ ushort_t f2bf(float f) {
    union { float f; uint32 i; } x; x.f = f;
    uint32 r = x.i + 0x7FFFu + ((x.i >> 16) & 1u);   // RNE (no NaN inputs)
    return (ushort_t)(r >> 16);
}

// ---------------------------------------------------------------------------
// Pack all 8 weight matrices (both layers) to Bt[layer][col][k] bf16.
// grid 512 x 256.
// ---------------------------------------------------------------------------
__global__ void pack_w2(const float* __restrict__ Wq1, const float* __restrict__ Wk1,
                        const float* __restrict__ Wv1, const float* __restrict__ Ws1,
                        const float* __restrict__ Wq2, const float* __restrict__ Wk2,
                        const float* __restrict__ Wv2, const float* __restrict__ Ws2,
                        ushort_t* __restrict__ Bt1, ushort_t* __restrict__ Bt2)
{
    int idx = blockIdx.x * 256 + threadIdx.x;        // [0, 131072)
    int layer = idx >> 16;
    int r = idx & 65535;
    int col = r >> 7;                                 // [0,512)
    int kk = r & 127;
    int wsel = col >> 7;
    const float* W = (layer == 0)
        ? ((wsel == 0) ? Wq1 : (wsel == 1) ? Wk1 : (wsel == 2) ? Wv1 : Ws1)
        : ((wsel == 0) ? Wq2 : (wsel == 1) ? Wk2 : (wsel == 2) ? Wv2 : Ws2);
    (layer == 0 ? Bt1 : Bt2)[r] = f2bf(W[kk * HID + (col & 127)]);
}

// ---------------------------------------------------------------------------
// MFMA GEMM: grid = 8*MT flat; block handles one (mtile, weight, 64-col half).
// XCD-bijective swizzle: blocks sharing an A-tile land on the same XCD so the
// A panel (~1.6MB/XCD) stays L2-resident. LAYER 1 converts fp32 X on the fly.
// Outputs: Q -> Qb[128/node], K/V -> KVb interleaved [K 128 | V 128]/node,
// skip -> Sf fp32.
// ---------------------------------------------------------------------------
template <int LAYER>
__global__ __launch_bounds__(256, 5) void gemm_mfma(
    const float* __restrict__ Xf, const ushort_t* __restrict__ Xh,
    const ushort_t* __restrict__ Bt,
    const float* __restrict__ bqp, const float* __restrict__ bkp,
    const float* __restrict__ bvp, const float* __restrict__ bsp,
    ushort_t* __restrict__ Qb, ushort_t* __restrict__ KVb, float* __restrict__ Sf)
{
    __shared__ ushort_t As[64 * 128];    // 16KB (reused as fp32 C-tile)
    __shared__ ushort_t Bs[64 * 128];    // 16KB
    const int wgid = blockIdx.x;
    const int xcd = wgid & 7, kidx = wgid >> 3;
    const int local = xcd * MT + kidx;               // XCD x owns a contiguous chunk
    const int mtile = local >> 3;
    const int gg = local & 7;
    const int g = gg >> 1;                           // 0=q 1=k 2=v 3=skip
    const int colbase = (gg & 1) * 64;
    const int Mbase = mtile * 64;
    const int tid = threadIdx.x;
    const int lane = tid & 63, wave = tid >> 6;

    #pragma unroll
    for (int it = 0; it < 4; ++it) {                 // A: 1024 x 16B segs
        int lin = it * 256 + tid;
        int row = lin >> 4, s = lin & 15;
        int rg = Mbase + row; if (rg >= NN) rg = NN - 1;
        short8 v;
        if (LAYER == 1) {
            float4 f0 = *reinterpret_cast<const float4*>(Xf + (size_t)rg * HID + s * 8);
            float4 f1 = *reinterpret_cast<const float4*>(Xf + (size_t)rg * HID + s * 8 + 4);
            v[0] = (short)f2bf(f0.x); v[1] = (short)f2bf(f0.y);
            v[2] = (short)f2bf(f0.z); v[3] = (short)f2bf(f0.w);
            v[4] = (short)f2bf(f1.x); v[5] = (short)f2bf(f1.y);
            v[6] = (short)f2bf(f1.z); v[7] = (short)f2bf(f1.w);
        } else {
            v = *reinterpret_cast<const short8*>(Xh + (size_t)rg * HID + s * 8);
        }
        *reinterpret_cast<short8*>((char*)As + row * 256 + ((s * 16) ^ ((row & 7) * 16))) = v;
    }
    #pragma unroll
    for (int it = 0; it < 4; ++it) {                 // B: 64 cols
        int lin = it * 256 + tid;
        int col = lin >> 4, s = lin & 15;
        short8 v = *reinterpret_cast<const short8*>(
            Bt + (size_t)(g * 128 + colbase + col) * HID + s * 8);
        *reinterpret_cast<short8*>((char*)Bs + col * 256 + ((s * 16) ^ ((col & 7) * 16))) = v;
    }
    __syncthreads();

    const int l15 = lane & 15;
    const int wrow = wave * 16;
    f32x4 acc[4] = {};
    #pragma unroll
    for (int kk = 0; kk < 4; ++kk) {
        int kbyte = kk * 64 + (lane >> 4) * 16;
        int ar = wrow + l15;
        short8 a = *reinterpret_cast<const short8*>(
            (const char*)As + ar * 256 + (kbyte ^ ((ar & 7) * 16)));
        #pragma unroll
        for (int nb = 0; nb < 4; ++nb) {
            int c = nb * 16 + l15;
            short8 b = *reinterpret_cast<const short8*>(
                (const char*)Bs + c * 256 + (kbyte ^ ((c & 7) * 16)));
            acc[nb] = __builtin_amdgcn_mfma_f32_16x16x32_bf16(a, b, acc[nb], 0, 0, 0);
        }
    }
    __syncthreads();                                 // done reading As/Bs

    const float* bias = (g == 0) ? bqp : (g == 1) ? bkp : (g == 2) ? bvp : bsp;
    float* Cs = reinterpret_cast<float*>(As);        // 64x64 fp32 = 16KB
    #pragma unroll
    for (int nb = 0; nb < 4; ++nb) {
        int c = nb * 16 + l15;
        float bb = bias[colbase + c];
        #pragma unroll
        for (int r = 0; r < 4; ++r) {
            int rl = wrow + (lane >> 4) * 4 + r;     // C/D: col=lane&15, row=(lane>>4)*4+reg
            Cs[rl * 64 + c] = acc[nb][r] + bb;
        }
    }
    __syncthreads();

    if (g == 3) {
        #pragma unroll
        for (int it = 0; it < 4; ++it) {             // 64 rows x 64 cols fp32
            int lin = it * 256 + tid;
            int row = lin >> 4, s = lin & 15;
            int rg = Mbase + row;
            if (rg < NN) {
                float4 v = *reinterpret_cast<float4*>(&Cs[row * 64 + s * 4]);
                *reinterpret_cast<float4*>(&Sf[(size_t)rg * HID + colbase + s * 4]) = v;
            }
        }
    } else {
        #pragma unroll
        for (int it = 0; it < 2; ++it) {             // 64 rows x 64 cols bf16
            int lin = it * 256 + tid;
            int row = lin >> 3, s = lin & 7;
            int rg = Mbase + row;
            if (rg < NN) {
                float4 v0 = *reinterpret_cast<float4*>(&Cs[row * 64 + s * 8]);
                float4 v1 = *reinterpret_cast<float4*>(&Cs[row * 64 + s * 8 + 4]);
                short8 o;
                o[0] = (short)f2bf(v0.x); o[1] = (short)f2bf(v0.y);
                o[2] = (short)f2bf(v0.z); o[3] = (short)f2bf(v0.w);
                o[4] = (short)f2bf(v1.x); o[5] = (short)f2bf(v1.y);
                o[6] = (short)f2bf(v1.z); o[7] = (short)f2bf(v1.w);
                ushort_t* dst = (g == 0) ? (Qb  + (size_t)rg * HID + colbase + s * 8)
                              : (g == 1) ? (KVb + (size_t)rg * 256 + colbase + s * 8)
                              :            (KVb + (size_t)rg * 256 + 128 + colbase + s * 8);
                *reinterpret_cast<short8*>(dst) = o;
            }
        }
    }
}

// ---------------------------------------------------------------------------
// CSR build
// ---------------------------------------------------------------------------
__global__ void zero_i32(int* __restrict__ p, int n)
{
    int i = blockIdx.x * blockDim.x + threadIdx.x;
    if (i < n) p[i] = 0;
}

__global__ void hist_kernel(const int* __restrict__ dst, int* __restrict__ counts)
{
    int e = blockIdx.x * blockDim.x + threadIdx.x;
    if (e < NE) atomicAdd(&counts[dst[e]], 1);
}

__global__ __launch_bounds__(1024) void scan_kernel(
    const int* __restrict__ counts, int* __restrict__ offsets, int* __restrict__ cursor)
{
    __shared__ int part[1024];
    const int t = threadIdx.x;
    const int chunk = (NN + 1023) >> 10;               // 49
    const int beg = t * chunk;
    const int end = min(beg + chunk, NN);
    int s = 0;
    for (int i = beg; i < end; ++i) s += counts[i];
    part[t] = s;
    __syncthreads();
    for (int off = 1; off < 1024; off <<= 1) {
        int v = (t >= off) ? part[t - off] : 0;
        __syncthreads();
        part[t] += v;
        __syncthreads();
    }
    int run = (t > 0) ? part[t - 1] : 0;               // exclusive prefix
    for (int i = beg; i < end; ++i) {
        offsets[i] = run; cursor[i] = run; run += counts[i];
    }
    if (t == 1023) offsets[NN] = run;                  // == NE
}

__global__ void scatter_kernel(const int* __restrict__ src, const int* __restrict__ dst,
                               int* __restrict__ cursor, int* __restrict__ csr_src)
{
    int e = blockIdx.x * blockDim.x + threadIdx.x;
    if (e < NE) {
        int pos = atomicAdd(&cursor[dst[e]], 1);
        csr_src[pos] = src[e];
    }
}

// ---------------------------------------------------------------------------
// Edge aggregation: ONE WAVE PER EDGE ITERATION, all indices wave-uniform so
// csr_src/offsets go through scalar loads and KV-row addresses are SALU.
// Lane owns dims {2l, 2l+1}; head = lane>>3 (8 lanes, shfl_xor 1,2,4).
// KV interleaved: node row = [K 128 | V 128] ushorts, one base, V at +256B.
// Softmax without max-sub (scores O(10), fp32-safe; PyG eps negligible).
// ---------------------------------------------------------------------------
template <int LAYER>
__global__ __launch_bounds__(256) void edge_aggregate(
    const ushort_t* __restrict__ Qb, const ushort_t* __restrict__ KVb,
    const float* __restrict__ Sf,
    const int* __restrict__ offsets, const int* __restrict__ csr_src,
    const float* __restrict__ xres, const float* __restrict__ prelu_w,
    float* __restrict__ outF, ushort_t* __restrict__ outB)
{
    const int lane = threadIdx.x & 63;
    const int wid  = __builtin_amdgcn_readfirstlane((int)(threadIdx.x >> 6));
    const int node = blockIdx.x * 4 + wid;             // wave-uniform (SGPR)
    const int d2 = lane * 2;

    uint32 qu = *reinterpret_cast<const uint32*>(Qb + (size_t)node * HID + d2);
    const float q0 = bflo(qu) * 0.25f;                 // fold 1/sqrt(16)
    const float q1 = bfhi(qu) * 0.25f;

    const int beg = offsets[node];                     // scalar loads
    const int end = offsets[node + 1];

    float den = 0.f, a0 = 0.f, a1 = 0.f;

#define EDGE_STEP(SS) {                                                        \
        const ushort_t* kv = KVb + (size_t)(SS) * 256;                         \
        uint32 ku = *reinterpret_cast<const uint32*>(kv + d2);                 \
        uint32 vu = *reinterpret_cast<const uint32*>(kv + 128 + d2);           \
        float p = q0 * bflo(ku) + q1 * bfhi(ku);                               \
        p += __shfl_xor(p, 1); p += __shfl_xor(p, 2); p += __shfl_xor(p, 4);   \
        float w = __expf(p);                                                   \
        den += w;                                                              \
        a0 += w * bflo(vu);                                                    \
        a1 += w * bfhi(vu); }

    int i = beg;
    for (; i + 4 <= end; i += 4) {
        int s0 = csr_src[i];
        int s1 = csr_src[i + 1];
        int s2 = csr_src[i + 2];
        int s3 = csr_src[i + 3];
        EDGE_STEP(s0) EDGE_STEP(s1) EDGE_STEP(s2) EDGE_STEP(s3)
    }
    for (; i < end; ++i) {
        int s = csr_src[i];
        EDGE_STEP(s)
    }
#undef EDGE_STEP

    float inv = (den > 0.f) ? 1.f / den : 0.f;
    float2 sv = *reinterpret_cast<const float2*>(Sf + (size_t)node * HID + d2);
    float r0 = a0 * inv + sv.x;
    float r1 = a1 * inv + sv.y;
    if (LAYER == 2) {
        float2 xr = *reinterpret_cast<const float2*>(xres + (size_t)node * HID + d2);
        r0 += xr.x; r1 += xr.y;
    }
    const float al = prelu_w[0];
    r0 = fmaxf(r0, 0.f) + al * fminf(r0, 0.f);
    r1 = fmaxf(r1, 0.f) + al * fminf(r1, 0.f);
    if (LAYER == 1) {
        uint32 o = (uint32)f2bf(r0) | ((uint32)f2bf(r1) << 16);
        *reinterpret_cast<uint32*>(outB + (size_t)node * HID + d2) = o;
    } else {
        float2 o; o.x = r0; o.y = r1;
        *reinterpret_cast<float2*>(outF + (size_t)node * HID + d2) = o;
    }
}

// ---------------------------------------------------------------------------
extern "C" void kernel_launch(void* const* d_in, const int* in_sizes, int n_in,
                              void* d_out, int out_size, void* d_ws, size_t ws_size,
                              hipStream_t stream)
{
    const float* x       = (const float*)d_in[0];
    const int*   ei      = (const int*)d_in[1];
    const float* prelu_w = (const float*)d_in[2];
    const float* Wq1 = (const float*)d_in[3],  *bq1 = (const float*)d_in[4];
    const float* Wk1 = (const float*)d_in[5],  *bk1 = (const float*)d_in[6];
    const float* Wv1 = (const float*)d_in[7],  *bv1 = (const float*)d_in[8];
    const float* Ws1 = (const float*)d_in[9],  *bs1 = (const float*)d_in[10];
    const float* Wq2 = (const float*)d_in[11], *bq2 = (const float*)d_in[12];
    const float* Wk2 = (const float*)d_in[13], *bk2 = (const float*)d_in[14];
    const float* Wv2 = (const float*)d_in[15], *bv2 = (const float*)d_in[16];
    const float* Ws2 = (const float*)d_in[17], *bs2 = (const float*)d_in[18];

    char* w = (char*)d_ws;
    size_t off = 0;
    auto alloc = [&](size_t bytes) { void* p = w + off; off += (bytes + 255) & ~(size_t)255; return p; };
    ushort_t* x1b  = (ushort_t*)alloc((size_t)NN * HID * 2);    // 12.8 MB
    ushort_t* Qb   = (ushort_t*)alloc((size_t)NN * HID * 2);    // 12.8 MB
    ushort_t* KVb  = (ushort_t*)alloc((size_t)NN * 256 * 2);    // 25.6 MB interleaved K|V
    float*    Sf   = (float*)alloc((size_t)NN * HID * 4);       // 25.6 MB
    ushort_t* Bt1  = (ushort_t*)alloc((size_t)512 * 128 * 2);
    ushort_t* Bt2  = (ushort_t*)alloc((size_t)512 * 128 * 2);
    int* counts  = (int*)alloc(NN * sizeof(int));
    int* offsets = (int*)alloc((NN + 1) * sizeof(int));
    int* cursor  = (int*)alloc(NN * sizeof(int));
    int* csr_src = (int*)alloc(NE * sizeof(int));
    (void)ws_size; (void)in_sizes; (void)n_in; (void)out_size;

    const int* srcIdx = ei;
    const int* dstIdx = ei + NE;

    // CSR build (shared by both layers)
    zero_i32<<<(NN + 255) / 256, 256, 0, stream>>>(counts, NN);
    hist_kernel<<<(NE + 255) / 256, 256, 0, stream>>>(dstIdx, counts);
    scan_kernel<<<1, 1024, 0, stream>>>(counts, offsets, cursor);
    scatter_kernel<<<(NE + 255) / 256, 256, 0, stream>>>(srcIdx, dstIdx, cursor, csr_src);

    // weight packing (both layers, one launch)
    pack_w2<<<512, 256, 0, stream>>>(Wq1, Wk1, Wv1, Ws1, Wq2, Wk2, Wv2, Ws2, Bt1, Bt2);

    const int ggemm = 8 * MT;

    // ---- layer 1 ----
    gemm_mfma<1><<<ggemm, 256, 0, stream>>>(x, nullptr, Bt1, bq1, bk1, bv1, bs1,
                                            Qb, KVb, Sf);
    edge_aggregate<1><<<NN / 4, 256, 0, stream>>>(Qb, KVb, Sf, offsets, csr_src,
                                                  nullptr, prelu_w, nullptr, x1b);
    // ---- layer 2 ----
    gemm_mfma<2><<<ggemm, 256, 0, stream>>>(nullptr, x1b, Bt2, bq2, bk2, bv2, bs2,
                                            Qb, KVb, Sf);
    edge_aggregate<2><<<NN / 4, 256, 0, stream>>>(Qb, KVb, Sf, offsets, csr_src,
                                                  x, prelu_w, (float*)d_out, nullptr);
}

// Round 5
// 198.602 us; speedup vs baseline: 1.5145x; 1.5145x over previous
//
#include <hip/hip_runtime.h>

#define NN 50000
#define NE 500000
#define HID 128
#define MT 782   // ceil(NN/64)

typedef __attribute__((ext_vector_type(8))) short short8;   // 8 bf16 = 16B
typedef __attribute__((ext_vector_type(4))) float f32x4;
typedef unsigned short ushort_t;
typedef unsigned int uint32;

__device__ __forceinline__ float bflo(uint32 u) {
    union { float f; uint32 i; } x; x.i = u << 16; return x.f;
}
__device__ __forceinline__ float bfhi(uint32 u) {
    union { float f; uint32 i; } x; x.i = u & 0xffff0000u; return x.f;
}
__device__ __forceinline__ ushort_t f2bf(float f) {
    union { float f; uint32 i; } x; x.f = f;
    uint32 r = x.i + 0x7FFFu + ((x.i >> 16) & 1u);   // RNE (no NaN inputs)
    return (ushort_t)(r >> 16);
}

// ---------------------------------------------------------------------------
// Pack all 8 weight matrices (both layers) to Bt[layer][col][k] bf16.
// ---------------------------------------------------------------------------
__global__ void pack_w2(const float* __restrict__ Wq1, const float* __restrict__ Wk1,
                        const float* __restrict__ Wv1, const float* __restrict__ Ws1,
                        const float* __restrict__ Wq2, const float* __restrict__ Wk2,
                        const float* __restrict__ Wv2, const float* __restrict__ Ws2,
                        ushort_t* __restrict__ Bt1, ushort_t* __restrict__ Bt2)
{
    int idx = blockIdx.x * 256 + threadIdx.x;        // [0, 131072)
    int layer = idx >> 16;
    int r = idx & 65535;
    int col = r >> 7;                                 // [0,512)
    int kk = r & 127;
    int wsel = col >> 7;
    const float* W = (layer == 0)
        ? ((wsel == 0) ? Wq1 : (wsel == 1) ? Wk1 : (wsel == 2) ? Wv1 : Ws1)
        : ((wsel == 0) ? Wq2 : (wsel == 1) ? Wk2 : (wsel == 2) ? Wv2 : Ws2);
    (layer == 0 ? Bt1 : Bt2)[r] = f2bf(W[kk * HID + (col & 127)]);
}

// ---------------------------------------------------------------------------
// MFMA GEMM: grid = 8*MT flat; block handles one (mtile, weight, 64-col half).
// XCD-bijective swizzle keeps A-panels L2-local. LAYER 1 converts fp32 X on
// the fly. Outputs: Q -> Qb, K/V -> KVb interleaved [K|V]/node, skip -> Sf.
// ---------------------------------------------------------------------------
template <int LAYER>
__global__ __launch_bounds__(256, 5) void gemm_mfma(
    const float* __restrict__ Xf, const ushort_t* __restrict__ Xh,
    const ushort_t* __restrict__ Bt,
    const float* __restrict__ bqp, const float* __restrict__ bkp,
    const float* __restrict__ bvp, const float* __restrict__ bsp,
    ushort_t* __restrict__ Qb, ushort_t* __restrict__ KVb, float* __restrict__ Sf)
{
    __shared__ ushort_t As[64 * 128];    // 16KB (reused as fp32 C-tile)
    __shared__ ushort_t Bs[64 * 128];    // 16KB
    const int wgid = blockIdx.x;
    const int xcd = wgid & 7, kidx = wgid >> 3;
    const int local = xcd * MT + kidx;               // XCD x owns a contiguous chunk
    const int mtile = local >> 3;
    const int gg = local & 7;
    const int g = gg >> 1;                           // 0=q 1=k 2=v 3=skip
    const int colbase = (gg & 1) * 64;
    const int Mbase = mtile * 64;
    const int tid = threadIdx.x;
    const int lane = tid & 63, wave = tid >> 6;

    #pragma unroll
    for (int it = 0; it < 4; ++it) {                 // A: 1024 x 16B segs
        int lin = it * 256 + tid;
        int row = lin >> 4, s = lin & 15;
        int rg = Mbase + row; if (rg >= NN) rg = NN - 1;
        short8 v;
        if (LAYER == 1) {
            float4 f0 = *reinterpret_cast<const float4*>(Xf + (size_t)rg * HID + s * 8);
            float4 f1 = *reinterpret_cast<const float4*>(Xf + (size_t)rg * HID + s * 8 + 4);
            v[0] = (short)f2bf(f0.x); v[1] = (short)f2bf(f0.y);
            v[2] = (short)f2bf(f0.z); v[3] = (short)f2bf(f0.w);
            v[4] = (short)f2bf(f1.x); v[5] = (short)f2bf(f1.y);
            v[6] = (short)f2bf(f1.z); v[7] = (short)f2bf(f1.w);
        } else {
            v = *reinterpret_cast<const short8*>(Xh + (size_t)rg * HID + s * 8);
        }
        *reinterpret_cast<short8*>((char*)As + row * 256 + ((s * 16) ^ ((row & 7) * 16))) = v;
    }
    #pragma unroll
    for (int it = 0; it < 4; ++it) {                 // B: 64 cols
        int lin = it * 256 + tid;
        int col = lin >> 4, s = lin & 15;
        short8 v = *reinterpret_cast<const short8*>(
            Bt + (size_t)(g * 128 + colbase + col) * HID + s * 8);
        *reinterpret_cast<short8*>((char*)Bs + col * 256 + ((s * 16) ^ ((col & 7) * 16))) = v;
    }
    __syncthreads();

    const int l15 = lane & 15;
    const int wrow = wave * 16;
    f32x4 acc[4] = {};
    #pragma unroll
    for (int kk = 0; kk < 4; ++kk) {
        int kbyte = kk * 64 + (lane >> 4) * 16;
        int ar = wrow + l15;
        short8 a = *reinterpret_cast<const short8*>(
            (const char*)As + ar * 256 + (kbyte ^ ((ar & 7) * 16)));
        #pragma unroll
        for (int nb = 0; nb < 4; ++nb) {
            int c = nb * 16 + l15;
            short8 b = *reinterpret_cast<const short8*>(
                (const char*)Bs + c * 256 + (kbyte ^ ((c & 7) * 16)));
            acc[nb] = __builtin_amdgcn_mfma_f32_16x16x32_bf16(a, b, acc[nb], 0, 0, 0);
        }
    }
    __syncthreads();                                 // done reading As/Bs

    const float* bias = (g == 0) ? bqp : (g == 1) ? bkp : (g == 2) ? bvp : bsp;
    float* Cs = reinterpret_cast<float*>(As);        // 64x64 fp32 = 16KB
    #pragma unroll
    for (int nb = 0; nb < 4; ++nb) {
        int c = nb * 16 + l15;
        float bb = bias[colbase + c];
        #pragma unroll
        for (int r = 0; r < 4; ++r) {
            int rl = wrow + (lane >> 4) * 4 + r;     // C/D: col=lane&15, row=(lane>>4)*4+reg
            Cs[rl * 64 + c] = acc[nb][r] + bb;
        }
    }
    __syncthreads();

    if (g == 3) {
        #pragma unroll
        for (int it = 0; it < 4; ++it) {             // 64 rows x 64 cols fp32
            int lin = it * 256 + tid;
            int row = lin >> 4, s = lin & 15;
            int rg = Mbase + row;
            if (rg < NN) {
                float4 v = *reinterpret_cast<float4*>(&Cs[row * 64 + s * 4]);
                *reinterpret_cast<float4*>(&Sf[(size_t)rg * HID + colbase + s * 4]) = v;
            }
        }
    } else {
        #pragma unroll
        for (int it = 0; it < 2; ++it) {             // 64 rows x 64 cols bf16
            int lin = it * 256 + tid;
            int row = lin >> 3, s = lin & 7;
            int rg = Mbase + row;
            if (rg < NN) {
                float4 v0 = *reinterpret_cast<float4*>(&Cs[row * 64 + s * 8]);
                float4 v1 = *reinterpret_cast<float4*>(&Cs[row * 64 + s * 8 + 4]);
                short8 o;
                o[0] = (short)f2bf(v0.x); o[1] = (short)f2bf(v0.y);
                o[2] = (short)f2bf(v0.z); o[3] = (short)f2bf(v0.w);
                o[4] = (short)f2bf(v1.x); o[5] = (short)f2bf(v1.y);
                o[6] = (short)f2bf(v1.z); o[7] = (short)f2bf(v1.w);
                ushort_t* dst = (g == 0) ? (Qb  + (size_t)rg * HID + colbase + s * 8)
                              : (g == 1) ? (KVb + (size_t)rg * 256 + colbase + s * 8)
                              :            (KVb + (size_t)rg * 256 + 128 + colbase + s * 8);
                *reinterpret_cast<short8*>(dst) = o;
            }
        }
    }
}

// ---------------------------------------------------------------------------
// CSR build — hierarchical scan (rounds 2-3 version; single-block scan was
// a 110µs latency-bound disaster, see round-4 post-mortem).
// ---------------------------------------------------------------------------
__global__ void zero_i32(int* __restrict__ p, int n)
{
    int i = blockIdx.x * blockDim.x + threadIdx.x;
    if (i < n) p[i] = 0;
}

__global__ void hist_kernel(const int* __restrict__ dst, int* __restrict__ counts)
{
    int e = blockIdx.x * blockDim.x + threadIdx.x;
    if (e < NE) atomicAdd(&counts[dst[e]], 1);
}

#define SCAN_B 196   // ceil(NN/256)

__global__ __launch_bounds__(256) void block_sums(const int* __restrict__ counts,
                                                  int* __restrict__ bsum)
{
    int i = blockIdx.x * 256 + threadIdx.x;
    int v = (i < NN) ? counts[i] : 0;
    #pragma unroll
    for (int o = 1; o < 64; o <<= 1) v += __shfl_xor(v, o);
    __shared__ int ws[4];
    if ((threadIdx.x & 63) == 0) ws[threadIdx.x >> 6] = v;
    __syncthreads();
    if (threadIdx.x == 0) bsum[blockIdx.x] = ws[0] + ws[1] + ws[2] + ws[3];
}

__global__ __launch_bounds__(256) void scan_bsums(const int* __restrict__ bsum,
                                                  int* __restrict__ bbase)
{
    __shared__ int sh[256];
    int t = threadIdx.x;
    int v = (t < SCAN_B) ? bsum[t] : 0;
    sh[t] = v;
    __syncthreads();
    for (int o = 1; o < 256; o <<= 1) {
        int u = (t >= o) ? sh[t - o] : 0;
        __syncthreads();
        sh[t] += u;
        __syncthreads();
    }
    bbase[t] = (t > 0) ? sh[t - 1] : 0;
}

__global__ __launch_bounds__(256) void write_offsets(const int* __restrict__ counts,
        const int* __restrict__ bbase, int* __restrict__ offsets, int* __restrict__ cursor)
{
    __shared__ int sh[256];
    int t = threadIdx.x;
    int i = blockIdx.x * 256 + t;
    int v = (i < NN) ? counts[i] : 0;
    sh[t] = v;
    __syncthreads();
    for (int o = 1; o < 256; o <<= 1) {
        int u = (t >= o) ? sh[t - o] : 0;
        __syncthreads();
        sh[t] += u;
        __syncthreads();
    }
    int excl = sh[t] - v + bbase[blockIdx.x];
    if (i < NN) { offsets[i] = excl; cursor[i] = excl; }
    if (i == NN - 1) offsets[NN] = excl + v;             // == NE
}

__global__ void scatter_kernel(const int* __restrict__ src, const int* __restrict__ dst,
                               int* __restrict__ cursor, int* __restrict__ csr_src)
{
    int e = blockIdx.x * blockDim.x + threadIdx.x;
    if (e < NE) {
        int pos = atomicAdd(&cursor[dst[e]], 1);
        csr_src[pos] = src[e];
    }
}

// ---------------------------------------------------------------------------
// Edge aggregation: one wave per node, wave-uniform indices -> scalar loads
// for offsets/csr_src, SALU address math for KV rows. Lane owns dims
// {2l,2l+1}; head = lane>>3 (8 lanes, shfl_xor 1,2,4). KV interleaved.
// Softmax without max-sub (scores O(10), fp32-safe; PyG eps negligible).
// ---------------------------------------------------------------------------
template <int LAYER>
__global__ __launch_bounds__(256) void edge_aggregate(
    const ushort_t* __restrict__ Qb, const ushort_t* __restrict__ KVb,
    const float* __restrict__ Sf,
    const int* __restrict__ offsets, const int* __restrict__ csr_src,
    const float* __restrict__ xres, const float* __restrict__ prelu_w,
    float* __restrict__ outF, ushort_t* __restrict__ outB)
{
    const int lane = threadIdx.x & 63;
    const int wid  = __builtin_amdgcn_readfirstlane((int)(threadIdx.x >> 6));
    const int node = blockIdx.x * 4 + wid;             // wave-uniform (SGPR)
    const int d2 = lane * 2;

    uint32 qu = *reinterpret_cast<const uint32*>(Qb + (size_t)node * HID + d2);
    const float q0 = bflo(qu) * 0.25f;                 // fold 1/sqrt(16)
    const float q1 = bfhi(qu) * 0.25f;

    const int beg = offsets[node];                     // scalar loads
    const int end = offsets[node + 1];

    float den = 0.f, a0 = 0.f, a1 = 0.f;

#define EDGE_STEP(SS) {                                                        \
        const ushort_t* kv = KVb + (size_t)(SS) * 256;                         \
        uint32 ku = *reinterpret_cast<const uint32*>(kv + d2);                 \
        uint32 vu = *reinterpret_cast<const uint32*>(kv + 128 + d2);           \
        float p = q0 * bflo(ku) + q1 * bfhi(ku);                               \
        p += __shfl_xor(p, 1); p += __shfl_xor(p, 2); p += __shfl_xor(p, 4);   \
        float w = __expf(p);                                                   \
        den += w;                                                              \
        a0 += w * bflo(vu);                                                    \
        a1 += w * bfhi(vu); }

    int i = beg;
    for (; i + 4 <= end; i += 4) {
        int s0 = csr_src[i];
        int s1 = csr_src[i + 1];
        int s2 = csr_src[i + 2];
        int s3 = csr_src[i + 3];
        EDGE_STEP(s0) EDGE_STEP(s1) EDGE_STEP(s2) EDGE_STEP(s3)
    }
    for (; i < end; ++i) {
        int s = csr_src[i];
        EDGE_STEP(s)
    }
#undef EDGE_STEP

    float inv = (den > 0.f) ? 1.f / den : 0.f;
    float2 sv = *reinterpret_cast<const float2*>(Sf + (size_t)node * HID + d2);
    float r0 = a0 * inv + sv.x;
    float r1 = a1 * inv + sv.y;
    if (LAYER == 2) {
        float2 xr = *reinterpret_cast<const float2*>(xres + (size_t)node * HID + d2);
        r0 += xr.x; r1 += xr.y;
    }
    const float al = prelu_w[0];
    r0 = fmaxf(r0, 0.f) + al * fminf(r0, 0.f);
    r1 = fmaxf(r1, 0.f) + al * fminf(r1, 0.f);
    if (LAYER == 1) {
        uint32 o = (uint32)f2bf(r0) | ((uint32)f2bf(r1) << 16);
        *reinterpret_cast<uint32*>(outB + (size_t)node * HID + d2) = o;
    } else {
        float2 o; o.x = r0; o.y = r1;
        *reinterpret_cast<float2*>(outF + (size_t)node * HID + d2) = o;
    }
}

// ---------------------------------------------------------------------------
extern "C" void kernel_launch(void* const* d_in, const int* in_sizes, int n_in,
                              void* d_out, int out_size, void* d_ws, size_t ws_size,
                              hipStream_t stream)
{
    const float* x       = (const float*)d_in[0];
    const int*   ei      = (const int*)d_in[1];
    const float* prelu_w = (const float*)d_in[2];
    const float* Wq1 = (const float*)d_in[3],  *bq1 = (const float*)d_in[4];
    const float* Wk1 = (const float*)d_in[5],  *bk1 = (const float*)d_in[6];
    const float* Wv1 = (const float*)d_in[7],  *bv1 = (const float*)d_in[8];
    const float* Ws1 = (const float*)d_in[9],  *bs1 = (const float*)d_in[10];
    const float* Wq2 = (const float*)d_in[11], *bq2 = (const float*)d_in[12];
    const float* Wk2 = (const float*)d_in[13], *bk2 = (const float*)d_in[14];
    const float* Wv2 = (const float*)d_in[15], *bv2 = (const float*)d_in[16];
    const float* Ws2 = (const float*)d_in[17], *bs2 = (const float*)d_in[18];

    char* w = (char*)d_ws;
    size_t off = 0;
    auto alloc = [&](size_t bytes) { void* p = w + off; off += (bytes + 255) & ~(size_t)255; return p; };
    ushort_t* x1b  = (ushort_t*)alloc((size_t)NN * HID * 2);    // 12.8 MB
    ushort_t* Qb   = (ushort_t*)alloc((size_t)NN * HID * 2);    // 12.8 MB
    ushort_t* KVb  = (ushort_t*)alloc((size_t)NN * 256 * 2);    // 25.6 MB interleaved K|V
    float*    Sf   = (float*)alloc((size_t)NN * HID * 4);       // 25.6 MB
    ushort_t* Bt1  = (ushort_t*)alloc((size_t)512 * 128 * 2);
    ushort_t* Bt2  = (ushort_t*)alloc((size_t)512 * 128 * 2);
    int* counts  = (int*)alloc(NN * sizeof(int));
    int* bsum    = (int*)alloc(256 * sizeof(int));
    int* bbase   = (int*)alloc(256 * sizeof(int));
    int* offsets = (int*)alloc((NN + 1) * sizeof(int));
    int* cursor  = (int*)alloc(NN * sizeof(int));
    int* csr_src = (int*)alloc(NE * sizeof(int));
    (void)ws_size; (void)in_sizes; (void)n_in; (void)out_size;

    const int* srcIdx = ei;
    const int* dstIdx = ei + NE;

    // CSR build (shared by both layers)
    zero_i32<<<(NN + 255) / 256, 256, 0, stream>>>(counts, NN);
    hist_kernel<<<(NE + 255) / 256, 256, 0, stream>>>(dstIdx, counts);
    block_sums<<<SCAN_B, 256, 0, stream>>>(counts, bsum);
    scan_bsums<<<1, 256, 0, stream>>>(bsum, bbase);
    write_offsets<<<SCAN_B, 256, 0, stream>>>(counts, bbase, offsets, cursor);
    scatter_kernel<<<(NE + 255) / 256, 256, 0, stream>>>(srcIdx, dstIdx, cursor, csr_src);

    // weight packing (both layers, one launch)
    pack_w2<<<512, 256, 0, stream>>>(Wq1, Wk1, Wv1, Ws1, Wq2, Wk2, Wv2, Ws2, Bt1, Bt2);

    const int ggemm = 8 * MT;

    // ---- layer 1 ----
    gemm_mfma<1><<<ggemm, 256, 0, stream>>>(x, nullptr, Bt1, bq1, bk1, bv1, bs1,
                                            Qb, KVb, Sf);
    edge_aggregate<1><<<NN / 4, 256, 0, stream>>>(Qb, KVb, Sf, offsets, csr_src,
                                                  nullptr, prelu_w, nullptr, x1b);
    // ---- layer 2 ----
    gemm_mfma<2><<<ggemm, 256, 0, stream>>>(nullptr, x1b, Bt2, bq2, bk2, bv2, bs2,
                                            Qb, KVb, Sf);
    edge_aggregate<2><<<NN / 4, 256, 0, stream>>>(Qb, KVb, Sf, offsets, csr_src,
                                                  x, prelu_w, (float*)d_out, nullptr);
}

// Round 6
// 194.174 us; speedup vs baseline: 1.5490x; 1.0228x over previous
//
#include <hip/hip_runtime.h>

#define NN 50000
#define NE 500000
#define HID 128
#define MT 782   // ceil(NN/64)

typedef __attribute__((ext_vector_type(8))) short short8;   // 8 bf16 = 16B
typedef __attribute__((ext_vector_type(4))) float f32x4;
typedef unsigned short ushort_t;
typedef unsigned int uint32;

__device__ __forceinline__ float bflo(uint32 u) {
    union { float f; uint32 i; } x; x.i = u << 16; return x.f;
}
__device__ __forceinline__ float bfhi(uint32 u) {
    union { float f; uint32 i; } x; x.i = u & 0xffff0000u; return x.f;
}
__device__ __forceinline__ ushort_t f2bf(float f) {
    union { float f; uint32 i; } x; x.f = f;
    uint32 r = x.i + 0x7FFFu + ((x.i >> 16) & 1u);   // RNE (no NaN inputs)
    return (ushort_t)(r >> 16);
}

// ---------------------------------------------------------------------------
// Pack all 8 weight matrices (both layers) to Bt[layer][col][k] bf16.
// ---------------------------------------------------------------------------
__global__ void pack_w2(const float* __restrict__ Wq1, const float* __restrict__ Wk1,
                        const float* __restrict__ Wv1, const float* __restrict__ Ws1,
                        const float* __restrict__ Wq2, const float* __restrict__ Wk2,
                        const float* __restrict__ Wv2, const float* __restrict__ Ws2,
                        ushort_t* __restrict__ Bt1, ushort_t* __restrict__ Bt2)
{
    int idx = blockIdx.x * 256 + threadIdx.x;        // [0, 131072)
    int layer = idx >> 16;
    int r = idx & 65535;
    int col = r >> 7;                                 // [0,512)
    int kk = r & 127;
    int wsel = col >> 7;
    const float* W = (layer == 0)
        ? ((wsel == 0) ? Wq1 : (wsel == 1) ? Wk1 : (wsel == 2) ? Wv1 : Ws1)
        : ((wsel == 0) ? Wq2 : (wsel == 1) ? Wk2 : (wsel == 2) ? Wv2 : Ws2);
    (layer == 0 ? Bt1 : Bt2)[r] = f2bf(W[kk * HID + (col & 127)]);
}

// ---------------------------------------------------------------------------
// MFMA GEMM: grid = 8*MT flat; block handles one (mtile, weight, 64-col half).
// XCD-bijective swizzle keeps A-panels L2-local. LAYER 1 converts fp32 X on
// the fly. All outputs bf16: Q -> Qb, K/V -> KVb interleaved, skip -> Sfb.
// ---------------------------------------------------------------------------
template <int LAYER>
__global__ __launch_bounds__(256, 5) void gemm_mfma(
    const float* __restrict__ Xf, const ushort_t* __restrict__ Xh,
    const ushort_t* __restrict__ Bt,
    const float* __restrict__ bqp, const float* __restrict__ bkp,
    const float* __restrict__ bvp, const float* __restrict__ bsp,
    ushort_t* __restrict__ Qb, ushort_t* __restrict__ KVb, ushort_t* __restrict__ Sfb)
{
    __shared__ ushort_t As[64 * 128];    // 16KB (reused as fp32 C-tile)
    __shared__ ushort_t Bs[64 * 128];    // 16KB
    const int wgid = blockIdx.x;
    const int xcd = wgid & 7, kidx = wgid >> 3;
    const int local = xcd * MT + kidx;               // XCD x owns a contiguous chunk
    const int mtile = local >> 3;
    const int gg = local & 7;
    const int g = gg >> 1;                           // 0=q 1=k 2=v 3=skip
    const int colbase = (gg & 1) * 64;
    const int Mbase = mtile * 64;
    const int tid = threadIdx.x;
    const int lane = tid & 63, wave = tid >> 6;

    #pragma unroll
    for (int it = 0; it < 4; ++it) {                 // A: 1024 x 16B segs
        int lin = it * 256 + tid;
        int row = lin >> 4, s = lin & 15;
        int rg = Mbase + row; if (rg >= NN) rg = NN - 1;
        short8 v;
        if (LAYER == 1) {
            float4 f0 = *reinterpret_cast<const float4*>(Xf + (size_t)rg * HID + s * 8);
            float4 f1 = *reinterpret_cast<const float4*>(Xf + (size_t)rg * HID + s * 8 + 4);
            v[0] = (short)f2bf(f0.x); v[1] = (short)f2bf(f0.y);
            v[2] = (short)f2bf(f0.z); v[3] = (short)f2bf(f0.w);
            v[4] = (short)f2bf(f1.x); v[5] = (short)f2bf(f1.y);
            v[6] = (short)f2bf(f1.z); v[7] = (short)f2bf(f1.w);
        } else {
            v = *reinterpret_cast<const short8*>(Xh + (size_t)rg * HID + s * 8);
        }
        *reinterpret_cast<short8*>((char*)As + row * 256 + ((s * 16) ^ ((row & 7) * 16))) = v;
    }
    #pragma unroll
    for (int it = 0; it < 4; ++it) {                 // B: 64 cols
        int lin = it * 256 + tid;
        int col = lin >> 4, s = lin & 15;
        short8 v = *reinterpret_cast<const short8*>(
            Bt + (size_t)(g * 128 + colbase + col) * HID + s * 8);
        *reinterpret_cast<short8*>((char*)Bs + col * 256 + ((s * 16) ^ ((col & 7) * 16))) = v;
    }
    __syncthreads();

    const int l15 = lane & 15;
    const int wrow = wave * 16;
    f32x4 acc[4] = {};
    #pragma unroll
    for (int kk = 0; kk < 4; ++kk) {
        int kbyte = kk * 64 + (lane >> 4) * 16;
        int ar = wrow + l15;
        short8 a = *reinterpret_cast<const short8*>(
            (const char*)As + ar * 256 + (kbyte ^ ((ar & 7) * 16)));
        #pragma unroll
        for (int nb = 0; nb < 4; ++nb) {
            int c = nb * 16 + l15;
            short8 b = *reinterpret_cast<const short8*>(
                (const char*)Bs + c * 256 + (kbyte ^ ((c & 7) * 16)));
            acc[nb] = __builtin_amdgcn_mfma_f32_16x16x32_bf16(a, b, acc[nb], 0, 0, 0);
        }
    }
    __syncthreads();                                 // done reading As/Bs

    const float* bias = (g == 0) ? bqp : (g == 1) ? bkp : (g == 2) ? bvp : bsp;
    float* Cs = reinterpret_cast<float*>(As);        // 64x64 fp32 = 16KB
    #pragma unroll
    for (int nb = 0; nb < 4; ++nb) {
        int c = nb * 16 + l15;
        float bb = bias[colbase + c];
        #pragma unroll
        for (int r = 0; r < 4; ++r) {
            int rl = wrow + (lane >> 4) * 4 + r;     // C/D: col=lane&15, row=(lane>>4)*4+reg
            Cs[rl * 64 + c] = acc[nb][r] + bb;
        }
    }
    __syncthreads();

    #pragma unroll
    for (int it = 0; it < 2; ++it) {                 // 64 rows x 64 cols bf16
        int lin = it * 256 + tid;
        int row = lin >> 3, s = lin & 7;
        int rg = Mbase + row;
        if (rg < NN) {
            float4 v0 = *reinterpret_cast<float4*>(&Cs[row * 64 + s * 8]);
            float4 v1 = *reinterpret_cast<float4*>(&Cs[row * 64 + s * 8 + 4]);
            short8 o;
            o[0] = (short)f2bf(v0.x); o[1] = (short)f2bf(v0.y);
            o[2] = (short)f2bf(v0.z); o[3] = (short)f2bf(v0.w);
            o[4] = (short)f2bf(v1.x); o[5] = (short)f2bf(v1.y);
            o[6] = (short)f2bf(v1.z); o[7] = (short)f2bf(v1.w);
            ushort_t* dst = (g == 0) ? (Qb  + (size_t)rg * HID + colbase + s * 8)
                          : (g == 1) ? (KVb + (size_t)rg * 256 + colbase + s * 8)
                          : (g == 2) ? (KVb + (size_t)rg * 256 + 128 + colbase + s * 8)
                          :            (Sfb + (size_t)rg * HID + colbase + s * 8);
            *reinterpret_cast<short8*>(dst) = o;
        }
    }
}

// ---------------------------------------------------------------------------
// CSR build — hierarchical scan.
// ---------------------------------------------------------------------------
__global__ void zero_i32(int* __restrict__ p, int n)
{
    int i = blockIdx.x * blockDim.x + threadIdx.x;
    if (i < n) p[i] = 0;
}

__global__ void hist_kernel(const int* __restrict__ dst, int* __restrict__ counts)
{
    int e = blockIdx.x * blockDim.x + threadIdx.x;
    if (e < NE) atomicAdd(&counts[dst[e]], 1);
}

#define SCAN_B 196   // ceil(NN/256)

__global__ __launch_bounds__(256) void block_sums(const int* __restrict__ counts,
                                                  int* __restrict__ bsum)
{
    int i = blockIdx.x * 256 + threadIdx.x;
    int v = (i < NN) ? counts[i] : 0;
    #pragma unroll
    for (int o = 1; o < 64; o <<= 1) v += __shfl_xor(v, o);
    __shared__ int ws[4];
    if ((threadIdx.x & 63) == 0) ws[threadIdx.x >> 6] = v;
    __syncthreads();
    if (threadIdx.x == 0) bsum[blockIdx.x] = ws[0] + ws[1] + ws[2] + ws[3];
}

__global__ __launch_bounds__(256) void scan_bsums(const int* __restrict__ bsum,
                                                  int* __restrict__ bbase)
{
    __shared__ int sh[256];
    int t = threadIdx.x;
    int v = (t < SCAN_B) ? bsum[t] : 0;
    sh[t] = v;
    __syncthreads();
    for (int o = 1; o < 256; o <<= 1) {
        int u = (t >= o) ? sh[t - o] : 0;
        __syncthreads();
        sh[t] += u;
        __syncthreads();
    }
    bbase[t] = (t > 0) ? sh[t - 1] : 0;
}

__global__ __launch_bounds__(256) void write_offsets(const int* __restrict__ counts,
        const int* __restrict__ bbase, int* __restrict__ offsets, int* __restrict__ cursor)
{
    __shared__ int sh[256];
    int t = threadIdx.x;
    int i = blockIdx.x * 256 + t;
    int v = (i < NN) ? counts[i] : 0;
    sh[t] = v;
    __syncthreads();
    for (int o = 1; o < 256; o <<= 1) {
        int u = (t >= o) ? sh[t - o] : 0;
        __syncthreads();
        sh[t] += u;
        __syncthreads();
    }
    int excl = sh[t] - v + bbase[blockIdx.x];
    if (i < NN) { offsets[i] = excl; cursor[i] = excl; }
    if (i == NN - 1) offsets[NN] = excl + v;             // == NE
}

__global__ void scatter_kernel(const int* __restrict__ src, const int* __restrict__ dst,
                               int* __restrict__ cursor, int* __restrict__ csr_src)
{
    int e = blockIdx.x * blockDim.x + threadIdx.x;
    if (e < NE) {
        int pos = atomicAdd(&cursor[dst[e]], 1);
        csr_src[pos] = src[e];
    }
}

// ---------------------------------------------------------------------------
// Edge aggregation: one wave per node, wave-uniform indices (scalar loads),
// explicit load-batch-then-compute in chunks of 8 edges so up to 16 KV-row
// loads are in flight per wave (round-5 version serialized at MLP~2, VGPR=16).
// Lane owns dims {2l,2l+1}; head = lane>>3. KV interleaved [K|V] per node.
// ---------------------------------------------------------------------------
template <int LAYER>
__global__ __launch_bounds__(256) void edge_aggregate(
    const ushort_t* __restrict__ Qb, const ushort_t* __restrict__ KVb,
    const ushort_t* __restrict__ Sfb,
    const int* __restrict__ offsets, const int* __restrict__ csr_src,
    const float* __restrict__ xres, const float* __restrict__ prelu_w,
    float* __restrict__ outF, ushort_t* __restrict__ outB)
{
    const int lane = threadIdx.x & 63;
    const int wid  = __builtin_amdgcn_readfirstlane((int)(threadIdx.x >> 6));
    const int node = blockIdx.x * 4 + wid;             // wave-uniform (SGPR)
    const int d2 = lane * 2;

    uint32 qu = *reinterpret_cast<const uint32*>(Qb + (size_t)node * HID + d2);
    const float q0 = bflo(qu) * 0.25f;                 // fold 1/sqrt(16)
    const float q1 = bfhi(qu) * 0.25f;

    const int beg = offsets[node];                     // scalar loads
    const int end = offsets[node + 1];

    float den = 0.f, a0 = 0.f, a1 = 0.f;

#define COMPUTE(KU, VU) {                                                      \
        float p = q0 * bflo(KU) + q1 * bfhi(KU);                               \
        p += __shfl_xor(p, 1); p += __shfl_xor(p, 2); p += __shfl_xor(p, 4);   \
        float w = __expf(p);                                                   \
        den += w;                                                              \
        a0 += w * bflo(VU);                                                    \
        a1 += w * bfhi(VU); }

    int i = beg;
    for (; i + 8 <= end; i += 8) {
        uint32 ku[8], vu[8];
        #pragma unroll
        for (int j = 0; j < 8; ++j) {
            int s = csr_src[i + j];
            const ushort_t* kv = KVb + (size_t)s * 256;
            ku[j] = *reinterpret_cast<const uint32*>(kv + d2);
            vu[j] = *reinterpret_cast<const uint32*>(kv + 128 + d2);
        }
        #pragma unroll
        for (int j = 0; j < 8; ++j) COMPUTE(ku[j], vu[j])
    }
    for (; i + 4 <= end; i += 4) {
        uint32 ku[4], vu[4];
        #pragma unroll
        for (int j = 0; j < 4; ++j) {
            int s = csr_src[i + j];
            const ushort_t* kv = KVb + (size_t)s * 256;
            ku[j] = *reinterpret_cast<const uint32*>(kv + d2);
            vu[j] = *reinterpret_cast<const uint32*>(kv + 128 + d2);
        }
        #pragma unroll
        for (int j = 0; j < 4; ++j) COMPUTE(ku[j], vu[j])
    }
    for (; i < end; ++i) {
        int s = csr_src[i];
        const ushort_t* kv = KVb + (size_t)s * 256;
        uint32 ku = *reinterpret_cast<const uint32*>(kv + d2);
        uint32 vu = *reinterpret_cast<const uint32*>(kv + 128 + d2);
        COMPUTE(ku, vu)
    }
#undef COMPUTE

    float inv = (den > 0.f) ? 1.f / den : 0.f;
    uint32 su = *reinterpret_cast<const uint32*>(Sfb + (size_t)node * HID + d2);
    float r0 = a0 * inv + bflo(su);
    float r1 = a1 * inv + bfhi(su);
    if (LAYER == 2) {
        float2 xr = *reinterpret_cast<const float2*>(xres + (size_t)node * HID + d2);
        r0 += xr.x; r1 += xr.y;
    }
    const float al = prelu_w[0];
    r0 = fmaxf(r0, 0.f) + al * fminf(r0, 0.f);
    r1 = fmaxf(r1, 0.f) + al * fminf(r1, 0.f);
    if (LAYER == 1) {
        uint32 o = (uint32)f2bf(r0) | ((uint32)f2bf(r1) << 16);
        *reinterpret_cast<uint32*>(outB + (size_t)node * HID + d2) = o;
    } else {
        float2 o; o.x = r0; o.y = r1;
        *reinterpret_cast<float2*>(outF + (size_t)node * HID + d2) = o;
    }
}

// ---------------------------------------------------------------------------
extern "C" void kernel_launch(void* const* d_in, const int* in_sizes, int n_in,
                              void* d_out, int out_size, void* d_ws, size_t ws_size,
                              hipStream_t stream)
{
    const float* x       = (const float*)d_in[0];
    const int*   ei      = (const int*)d_in[1];
    const float* prelu_w = (const float*)d_in[2];
    const float* Wq1 = (const float*)d_in[3],  *bq1 = (const float*)d_in[4];
    const float* Wk1 = (const float*)d_in[5],  *bk1 = (const float*)d_in[6];
    const float* Wv1 = (const float*)d_in[7],  *bv1 = (const float*)d_in[8];
    const float* Ws1 = (const float*)d_in[9],  *bs1 = (const float*)d_in[10];
    const float* Wq2 = (const float*)d_in[11], *bq2 = (const float*)d_in[12];
    const float* Wk2 = (const float*)d_in[13], *bk2 = (const float*)d_in[14];
    const float* Wv2 = (const float*)d_in[15], *bv2 = (const float*)d_in[16];
    const float* Ws2 = (const float*)d_in[17], *bs2 = (const float*)d_in[18];

    char* w = (char*)d_ws;
    size_t off = 0;
    auto alloc = [&](size_t bytes) { void* p = w + off; off += (bytes + 255) & ~(size_t)255; return p; };
    ushort_t* x1b  = (ushort_t*)alloc((size_t)NN * HID * 2);    // 12.8 MB
    ushort_t* Qb   = (ushort_t*)alloc((size_t)NN * HID * 2);    // 12.8 MB
    ushort_t* KVb  = (ushort_t*)alloc((size_t)NN * 256 * 2);    // 25.6 MB interleaved K|V
    ushort_t* Sfb  = (ushort_t*)alloc((size_t)NN * HID * 2);    // 12.8 MB
    ushort_t* Bt1  = (ushort_t*)alloc((size_t)512 * 128 * 2);
    ushort_t* Bt2  = (ushort_t*)alloc((size_t)512 * 128 * 2);
    int* counts  = (int*)alloc(NN * sizeof(int));
    int* bsum    = (int*)alloc(256 * sizeof(int));
    int* bbase   = (int*)alloc(256 * sizeof(int));
    int* offsets = (int*)alloc((NN + 1) * sizeof(int));
    int* cursor  = (int*)alloc(NN * sizeof(int));
    int* csr_src = (int*)alloc(NE * sizeof(int));
    (void)ws_size; (void)in_sizes; (void)n_in; (void)out_size;

    const int* srcIdx = ei;
    const int* dstIdx = ei + NE;

    // CSR build (shared by both layers)
    zero_i32<<<(NN + 255) / 256, 256, 0, stream>>>(counts, NN);
    hist_kernel<<<(NE + 255) / 256, 256, 0, stream>>>(dstIdx, counts);
    block_sums<<<SCAN_B, 256, 0, stream>>>(counts, bsum);
    scan_bsums<<<1, 256, 0, stream>>>(bsum, bbase);
    write_offsets<<<SCAN_B, 256, 0, stream>>>(counts, bbase, offsets, cursor);
    scatter_kernel<<<(NE + 255) / 256, 256, 0, stream>>>(srcIdx, dstIdx, cursor, csr_src);

    // weight packing (both layers, one launch)
    pack_w2<<<512, 256, 0, stream>>>(Wq1, Wk1, Wv1, Ws1, Wq2, Wk2, Wv2, Ws2, Bt1, Bt2);

    const int ggemm = 8 * MT;

    // ---- layer 1 ----
    gemm_mfma<1><<<ggemm, 256, 0, stream>>>(x, nullptr, Bt1, bq1, bk1, bv1, bs1,
                                            Qb, KVb, Sfb);
    edge_aggregate<1><<<NN / 4, 256, 0, stream>>>(Qb, KVb, Sfb, offsets, csr_src,
                                                  nullptr, prelu_w, nullptr, x1b);
    // ---- layer 2 ----
    gemm_mfma<2><<<ggemm, 256, 0, stream>>>(nullptr, x1b, Bt2, bq2, bk2, bv2, bs2,
                                            Qb, KVb, Sfb);
    edge_aggregate<2><<<NN / 4, 256, 0, stream>>>(Qb, KVb, Sfb, offsets, csr_src,
                                                  x, prelu_w, (float*)d_out, nullptr);
}